// Round 10
// baseline (30.702 us; speedup 1.0000x reference)
//
#include <hip/hip_runtime.h>

// out[b,h] = (X X^T) X == X (X^T X) per head; X = x[b,h] : [2048 x 64] fp32.
// MFMA bf16 (fp32 accumulate), 2 sync-free dispatches:
//  K1 (256 blocks, 256 rows): DMA f32 (2x128-row halves) -> convert to
//     (a) transposed swizzled XT for the Gram MFMA (K=256), and
//     (b) bf16 row-major swizzled X image -> ws (pre-swizzled GLOBAL layout
//         so K2 can DMA it linearly and read swizzled; m173 pattern).
//     Partial Gram (8 per head) via mfma_f32_16x16x32_bf16, cached stores.
//  K2 (256 blocks, 256 rows): DMA both bf16 tiles || redundant fixed-order
//     fp32 reduce of 8 partials -> G -> bf16 swizzled LDS; ONE barrier;
//     out = X*G via MFMA (G symmetric => B-operand row read).
// C/D layout per m89: col = lane&15, row = (lane>>4)*4 + reg.

#define TDIM 2048
#define DDIM 64
#define NHEADS 32

#define PART_FLOATS (NHEADS * 8 * 4096)          // 4 MB
#define XBF_SHORT_OFF ((size_t)PART_FLOATS * 2)  // xbf after part (in shorts)

typedef float f4 __attribute__((ext_vector_type(4)));
typedef float f32x4 __attribute__((ext_vector_type(4)));
typedef short bf16x8 __attribute__((ext_vector_type(8)));
typedef short s4 __attribute__((ext_vector_type(4)));

// Async global->LDS DMA, 16 B/lane. LDS dest wave-uniform; lane l -> dest+l*16.
__device__ __forceinline__ void async_copy16(const void* g, void* l) {
    __builtin_amdgcn_global_load_lds(
        (const __attribute__((address_space(1))) void*)g,
        (__attribute__((address_space(3))) void*)l, 16, 0, 0);
}

// f32 -> bf16 bits, round-to-nearest-even.
__device__ __forceinline__ short f2bf(float f) {
    unsigned u = __builtin_bit_cast(unsigned, f);
    unsigned r = (u + 0x7fffu + ((u >> 16) & 1u)) >> 16;
    return (short)r;
}

// Swizzled fragment pointer: row-major bf16 tile (rowlen shorts/row); byte
// offset within row = (kelem*2) ^ ((row&7)<<4). 16 B alignment preserved.
__device__ __forceinline__ const bf16x8* fragp(const short* base, int row,
                                               int rowlen, int kelem) {
    const char* p = (const char*)(base + row * rowlen);
    return (const bf16x8*)(p + ((kelem * 2) ^ ((row & 7) << 4)));
}

// ---------------- K1: partial Gram + bf16 X emission ----------------
__global__ __launch_bounds__(256) void k1_gram(const float* __restrict__ x,
                                               float* __restrict__ part,
                                               short* __restrict__ xbf) {
    __shared__ __align__(16) float Sf[8192];      // 32 KB: 128-row f32 stage
    __shared__ __align__(16) short XT[64 * 256];  // 32 KB: transposed swz bf16

    const int b    = blockIdx.x;        // 0..255
    const int tid  = threadIdx.x;
    const int lane = tid & 63;
    const int w    = tid >> 6;
    const int head = b >> 3, ch = b & 7;
    const int tile_base = head * 16 + ch * 2;     // 128-row tile index

    const float* xh = x + ((size_t)head * TDIM + ch * 256) * DDIM;

#pragma unroll
    for (int half = 0; half < 2; ++half) {
        {   // DMA 128x64 f32 -> Sf
            const float* gs = xh + half * 8192 + w * 2048 + lane * 4;
            float* ld = Sf + w * 2048;
#pragma unroll
            for (int it = 0; it < 8; ++it)
                async_copy16(gs + it * 256, ld + it * 256);
        }
        __syncthreads();   // drains DMA (and prior-half Sf readers)

        // (a) convert + transpose into XT[c][t], swizzled
#pragma unroll 8
        for (int e = 0; e < 32; ++e) {
            const int idx = e * 256 + tid;
            const int r = idx >> 6, c = idx & 63;
            const int t = half * 128 + r;
            XT[c * 256 + ((((t << 1)) ^ ((c & 7) << 4)) >> 1)] = f2bf(Sf[idx]);
        }

        // (b) convert row-major -> global bf16 image (pre-swizzled layout)
        {
            short* xbt = xbf + (size_t)(tile_base + half) * 8192;
#pragma unroll
            for (int e = 0; e < 8; ++e) {
                const int i4 = e * 256 + tid;            // f4 id in 128x16
                const int r = i4 >> 4, c4 = (i4 & 15) << 2;
                const f4 v = *reinterpret_cast<const f4*>(Sf + (i4 << 2));
                s4 pk;
                pk[0] = f2bf(v[0]); pk[1] = f2bf(v[1]);
                pk[2] = f2bf(v[2]); pk[3] = f2bf(v[3]);
                *(s4*)((char*)xbt + r * 128 + (((c4 << 1)) ^ ((r & 7) << 4))) = pk;
            }
        }
        __syncthreads();   // Sf fully consumed before next-half DMA
    }

    // Gram MFMA over K=256: wave w owns 2x2 16x16 quad of G
    const int li = lane & 15, g = lane >> 4;
    const int iq0 = (w >> 1) * 2, jq0 = (w & 1) * 2;

    f32x4 acc[2][2];
#pragma unroll
    for (int a = 0; a < 2; ++a)
#pragma unroll
        for (int q = 0; q < 2; ++q) acc[a][q] = (f32x4){0.f, 0.f, 0.f, 0.f};

#pragma unroll
    for (int k0 = 0; k0 < 256; k0 += 32) {
        bf16x8 af[2], bv[2];
        af[0] = *fragp(XT, (iq0 + 0) * 16 + li, 256, k0 + 8 * g);
        af[1] = *fragp(XT, (iq0 + 1) * 16 + li, 256, k0 + 8 * g);
        bv[0] = *fragp(XT, (jq0 + 0) * 16 + li, 256, k0 + 8 * g);
        bv[1] = *fragp(XT, (jq0 + 1) * 16 + li, 256, k0 + 8 * g);
#pragma unroll
        for (int a = 0; a < 2; ++a)
#pragma unroll
            for (int q = 0; q < 2; ++q)
                acc[a][q] = __builtin_amdgcn_mfma_f32_16x16x32_bf16(
                    af[a], bv[q], acc[a][q], 0, 0, 0);
    }

    float* pp = part + (size_t)(head * 8 + ch) * 4096;
#pragma unroll
    for (int a = 0; a < 2; ++a)
#pragma unroll
        for (int d = 0; d < 2; ++d)
#pragma unroll
            for (int q = 0; q < 4; ++q)
                pp[((iq0 + a) * 16 + g * 4 + q) * 64 + (jq0 + d) * 16 + li] =
                    acc[a][d][q];
}

// ---------------- K2: reduce + XG via MFMA, one barrier ----------------
__global__ __launch_bounds__(256) void k2_xg(float* __restrict__ out,
                                             const float* __restrict__ part,
                                             const short* __restrict__ xbf) {
    __shared__ __align__(16) short Xb0[8192];     // 16 KB bf16 tile (swz image)
    __shared__ __align__(16) short Xb1[8192];
    __shared__ __align__(16) short Gb[4096];      // 8 KB bf16 G (swz)

    const int b    = blockIdx.x;        // 0..255
    const int tid  = threadIdx.x;
    const int lane = tid & 63;
    const int w    = tid >> 6;
    const int head = b >> 3, ch = b & 7;
    const int tile_base = head * 16 + ch * 2;

    {   // DMA both bf16 tiles (L3-hot; overlap the reduce below)
        const short* g0 = xbf + (size_t)tile_base * 8192 + w * 2048 + lane * 8;
        const short* g1 = g0 + 8192;
#pragma unroll
        for (int it = 0; it < 4; ++it) {
            async_copy16(g0 + it * 512, Xb0 + w * 2048 + it * 512);
            async_copy16(g1 + it * 512, Xb1 + w * 2048 + it * 512);
        }
    }

    // Redundant fixed-order reduce of 8 partials -> G -> bf16 swz LDS.
    {
        const float* ph = part + (size_t)head * 8 * 4096 + tid * 4;
        f4 av[4];
#pragma unroll
        for (int k = 0; k < 4; ++k) av[k] = (f4){0.f, 0.f, 0.f, 0.f};
#pragma unroll
        for (int c = 0; c < 8; ++c) {
            const float* pc = ph + (size_t)c * 4096;
#pragma unroll
            for (int k = 0; k < 4; ++k)
                av[k] += *reinterpret_cast<const f4*>(pc + k * 1024);
        }
#pragma unroll
        for (int k = 0; k < 4; ++k)
#pragma unroll
            for (int q = 0; q < 4; ++q) {
                const int idx = k * 1024 + tid * 4 + q;  // linear i*64+d
                const int i = idx >> 6, d = idx & 63;
                Gb[d * 64 + ((((i << 1)) ^ ((d & 7) << 4)) >> 1)] =
                    f2bf(av[k][q]);
            }
    }
    __syncthreads();   // drains both tile DMAs + publishes Gb

    const int li = lane & 15, g = lane >> 4;

#pragma unroll
    for (int half = 0; half < 2; ++half) {
        const short* Xs = half ? Xb1 : Xb0;
        f32x4 acc[2][4];
#pragma unroll
        for (int r = 0; r < 2; ++r)
#pragma unroll
            for (int d = 0; d < 4; ++d) acc[r][d] = (f32x4){0.f, 0.f, 0.f, 0.f};

#pragma unroll
        for (int k0 = 0; k0 < 64; k0 += 32) {
            bf16x8 af[2], bv[4];
            af[0] = *fragp(Xs, (w * 2 + 0) * 16 + li, 64, k0 + 8 * g);
            af[1] = *fragp(Xs, (w * 2 + 1) * 16 + li, 64, k0 + 8 * g);
#pragma unroll
            for (int d = 0; d < 4; ++d)
                bv[d] = *fragp(Gb, d * 16 + li, 64, k0 + 8 * g);
#pragma unroll
            for (int r = 0; r < 2; ++r)
#pragma unroll
                for (int d = 0; d < 4; ++d)
                    acc[r][d] = __builtin_amdgcn_mfma_f32_16x16x32_bf16(
                        af[r], bv[d], acc[r][d], 0, 0, 0);
        }

        float* oh = out + ((size_t)head * TDIM + ch * 256 + half * 128) * DDIM;
#pragma unroll
        for (int r = 0; r < 2; ++r)
#pragma unroll
            for (int d = 0; d < 4; ++d)
#pragma unroll
                for (int q = 0; q < 4; ++q)
                    oh[((w * 2 + r) * 16 + g * 4 + q) * 64 + d * 16 + li] =
                        acc[r][d][q];
    }
}

extern "C" void kernel_launch(void* const* d_in, const int* in_sizes, int n_in,
                              void* d_out, int out_size, void* d_ws, size_t ws_size,
                              hipStream_t stream) {
    const float* x = (const float*)d_in[0];
    float* out  = (float*)d_out;
    float* part = (float*)d_ws;                        // 4 MB f32
    short* xbf  = (short*)d_ws + XBF_SHORT_OFF;        // 8.4 MB bf16 image

    k1_gram<<<256, 256, 0, stream>>>(x, part, xbf);
    k2_xg<<<256, 256, 0, stream>>>(out, part, xbf);
}

// Round 11
// 20.421 us; speedup vs baseline: 1.5034x; 1.5034x over previous
//
#include <hip/hip_runtime.h>

// out[b,h] = (X X^T) X == X (X^T X) per head; X = x[b,h] : [2048 x 64] fp32.
// MFMA bf16 (fp32 accumulate), 3 light dispatches tuned for OCCUPANCY:
//  K1 (512 blocks, 128-row chunks): global->reg f4 loads, f2bf convert,
//     transpose-swizzled XT in LDS (16 KB, ONE barrier), 16 MFMA/wave,
//     row-major f32 partial store (16 per head).
//  K2a (128 blocks): fixed-order reduce 16 partials -> G; emit PRE-SWIZZLED
//     bf16 G image so K2b can DMA it linearly and read swizzled (m173).
//  K2b (1024 blocks, 64-row tiles): DMA f32 x-tile + bf16 G concurrently,
//     one convert pass, ONE barrier, 8 MFMA/wave, out.
// C/D layout per m89: col = lane&15, row = (lane>>4)*4 + reg.

#define TDIM 2048
#define DDIM 64
#define NHEADS 32
#define NCH 16                                    // 128-row chunks per head

#define PART_FLOATS ((size_t)NHEADS * NCH * 4096) // 8.4 MB f32

typedef float f4 __attribute__((ext_vector_type(4)));
typedef float f32x4 __attribute__((ext_vector_type(4)));
typedef short bf16x8 __attribute__((ext_vector_type(8)));
typedef short s4 __attribute__((ext_vector_type(4)));

// Async global->LDS DMA, 16 B/lane. LDS dest wave-uniform; lane l -> dest+l*16.
__device__ __forceinline__ void async_copy16(const void* g, void* l) {
    __builtin_amdgcn_global_load_lds(
        (const __attribute__((address_space(1))) void*)g,
        (__attribute__((address_space(3))) void*)l, 16, 0, 0);
}

// f32 -> bf16 bits, round-to-nearest-even.
__device__ __forceinline__ short f2bf(float f) {
    unsigned u = __builtin_bit_cast(unsigned, f);
    unsigned r = (u + 0x7fffu + ((u >> 16) & 1u)) >> 16;
    return (short)r;
}

// Swizzled fragment pointer: row-major bf16 tile (rowlen shorts/row); byte
// offset within row = (kelem*2) ^ ((row&7)<<4). 16 B alignment preserved.
__device__ __forceinline__ const bf16x8* fragp(const short* base, int row,
                                               int rowlen, int kelem) {
    const char* p = (const char*)(base + row * rowlen);
    return (const bf16x8*)(p + ((kelem * 2) ^ ((row & 7) << 4)));
}

// ---------------- K1: partial Gram (global->reg->XT, 1 barrier) -------------
__global__ __launch_bounds__(256) void k1_gram(const float* __restrict__ x,
                                               float* __restrict__ part) {
    __shared__ __align__(16) short XT[64 * 128];  // 16 KB transposed swz bf16

    const int b    = blockIdx.x;        // 0..511
    const int tid  = threadIdx.x;
    const int lane = tid & 63;
    const int w    = tid >> 6;
    const int head = b >> 4, ch = b & 15;

    const float* xh = x + ((size_t)head * TDIM + ch * 128) * DDIM;

    // 8 f4 loads/thread -> convert -> transpose-swizzled LDS writes.
#pragma unroll
    for (int e = 0; e < 8; ++e) {
        const int i4 = e * 256 + tid;            // f4 index in 128x64 tile
        const int r  = i4 >> 4;                  // row t (0..127)
        const int c4 = (i4 & 15) << 2;           // col d base
        const f4 v = *reinterpret_cast<const f4*>(xh + (size_t)i4 * 4);
#pragma unroll
        for (int j = 0; j < 4; ++j) {
            const int c = c4 + j;
            *(short*)((char*)XT + c * 256 + ((2 * r) ^ ((c & 7) << 4))) =
                f2bf(v[j]);
        }
    }
    __syncthreads();

    // Gram MFMA over K=128: wave w owns 2x2 quad of 16x16 G tiles.
    const int li = lane & 15, g = lane >> 4;
    const int iq0 = (w >> 1) * 2, jq0 = (w & 1) * 2;

    f32x4 acc[2][2];
#pragma unroll
    for (int a = 0; a < 2; ++a)
#pragma unroll
        for (int q = 0; q < 2; ++q) acc[a][q] = (f32x4){0.f, 0.f, 0.f, 0.f};

#pragma unroll
    for (int k0 = 0; k0 < 128; k0 += 32) {
        bf16x8 af[2], bv[2];
        af[0] = *fragp(XT, (iq0 + 0) * 16 + li, 128, k0 + 8 * g);
        af[1] = *fragp(XT, (iq0 + 1) * 16 + li, 128, k0 + 8 * g);
        bv[0] = *fragp(XT, (jq0 + 0) * 16 + li, 128, k0 + 8 * g);
        bv[1] = *fragp(XT, (jq0 + 1) * 16 + li, 128, k0 + 8 * g);
#pragma unroll
        for (int a = 0; a < 2; ++a)
#pragma unroll
            for (int q = 0; q < 2; ++q)
                acc[a][q] = __builtin_amdgcn_mfma_f32_16x16x32_bf16(
                    af[a], bv[q], acc[a][q], 0, 0, 0);
    }

    float* pp = part + (size_t)b * 4096;
#pragma unroll
    for (int a = 0; a < 2; ++a)
#pragma unroll
        for (int d = 0; d < 2; ++d)
#pragma unroll
            for (int q = 0; q < 4; ++q)
                pp[((iq0 + a) * 16 + g * 4 + q) * 64 + (jq0 + d) * 16 + li] =
                    acc[a][d][q];
}

// ---------------- K2a: reduce partials -> pre-swizzled bf16 G ---------------
__global__ __launch_bounds__(256) void k2a_reduce(const float* __restrict__ part,
                                                  short* __restrict__ gbf) {
    const int b    = blockIdx.x;        // 0..127 : (head, quarter)
    const int tid  = threadIdx.x;
    const int head = b >> 2, p = b & 3;

    const int idx4 = p * 1024 + tid * 4;          // flat i*64+j base
    const float* ph = part + (size_t)head * NCH * 4096 + idx4;

    f4 s = (f4){0.f, 0.f, 0.f, 0.f};
#pragma unroll
    for (int c = 0; c < NCH; ++c)
        s += *reinterpret_cast<const f4*>(ph + (size_t)c * 4096);

    const int i  = idx4 >> 6;
    const int j4 = idx4 & 63;
    s4 pk;
    pk[0] = f2bf(s[0]); pk[1] = f2bf(s[1]);
    pk[2] = f2bf(s[2]); pk[3] = f2bf(s[3]);
    // pre-swizzled image: row i (128 B), byte-in-row = (2*j4)^((i&7)<<4)
    *(s4*)((char*)gbf + (size_t)head * 8192 + i * 128 +
           ((2 * j4) ^ ((i & 7) << 4))) = pk;
}

// ---------------- K2b: out = X*G via MFMA (64-row tiles, 1 barrier) ---------
__global__ __launch_bounds__(256) void k2b_xg(const float* __restrict__ x,
                                              float* __restrict__ out,
                                              const short* __restrict__ gbf) {
    __shared__ __align__(16) float Sf[4096];      // 16 KB f32 x-tile
    __shared__ __align__(16) short Xb[4096];      // 8 KB bf16 swz
    __shared__ __align__(16) short Gb[4096];      // 8 KB bf16 G swz

    const int b    = blockIdx.x;        // 0..1023
    const int tid  = threadIdx.x;
    const int lane = tid & 63;
    const int w    = tid >> 6;
    const int head = b >> 5, ch = b & 31;

    const float* xh = x + ((size_t)head * TDIM + ch * 64) * DDIM;

    {   // DMA f32 x-tile (16 KB) + bf16 G (8 KB) concurrently
        const float* gs = xh + w * 1024 + lane * 4;
        float* ld = Sf + w * 1024;
        const short* gg = gbf + (size_t)head * 4096 + w * 1024 + lane * 8;
        short* lg = Gb + w * 1024;
#pragma unroll
        for (int it = 0; it < 4; ++it)
            async_copy16(gs + it * 256, ld + it * 256);
#pragma unroll
        for (int it = 0; it < 2; ++it)
            async_copy16(gg + it * 512, lg + it * 512);
    }
    __syncthreads();   // compiler drains vmcnt before s_barrier

    // Convert Sf -> Xb (row-major swz), 16 elems/thread.
#pragma unroll
    for (int e = 0; e < 4; ++e) {
        const int i4 = e * 256 + tid;            // f4 index in 64x64 tile
        const int r  = i4 >> 4;
        const int c4 = (i4 & 15) << 2;
        const f4 v = *reinterpret_cast<const f4*>(Sf + (size_t)i4 * 4);
        s4 pk;
        pk[0] = f2bf(v[0]); pk[1] = f2bf(v[1]);
        pk[2] = f2bf(v[2]); pk[3] = f2bf(v[3]);
        *(s4*)((char*)Xb + r * 128 + ((2 * c4) ^ ((r & 7) << 4))) = pk;
    }
    __syncthreads();

    // MFMA: wave w owns row-tile w (16 rows) x all 4 col-tiles, K=64.
    const int li = lane & 15, g = lane >> 4;

    f32x4 acc[4];
#pragma unroll
    for (int d = 0; d < 4; ++d) acc[d] = (f32x4){0.f, 0.f, 0.f, 0.f};

#pragma unroll
    for (int k0 = 0; k0 < 64; k0 += 32) {
        bf16x8 af, bv[4];
        af = *fragp(Xb, w * 16 + li, 64, k0 + 8 * g);
#pragma unroll
        for (int d = 0; d < 4; ++d)
            bv[d] = *fragp(Gb, d * 16 + li, 64, k0 + 8 * g);
#pragma unroll
        for (int d = 0; d < 4; ++d)
            acc[d] = __builtin_amdgcn_mfma_f32_16x16x32_bf16(
                af, bv[d], acc[d], 0, 0, 0);
    }

    float* oh = out + ((size_t)head * TDIM + ch * 64) * DDIM;
#pragma unroll
    for (int d = 0; d < 4; ++d)
#pragma unroll
        for (int q = 0; q < 4; ++q)
            oh[(w * 16 + g * 4 + q) * 64 + d * 16 + li] = acc[d][q];
}

extern "C" void kernel_launch(void* const* d_in, const int* in_sizes, int n_in,
                              void* d_out, int out_size, void* d_ws, size_t ws_size,
                              hipStream_t stream) {
    const float* x = (const float*)d_in[0];
    float* out  = (float*)d_out;
    float* part = (float*)d_ws;                     // 8.4 MB f32
    short* gbf  = (short*)((float*)d_ws + PART_FLOATS);  // 256 KB bf16

    k1_gram<<<NHEADS * NCH, 256, 0, stream>>>(x, part);
    k2a_reduce<<<128, 256, 0, stream>>>(part, gbf);
    k2b_xg<<<NHEADS * 32, 256, 0, stream>>>(x, out, gbf);
}

// Round 12
// 18.983 us; speedup vs baseline: 1.6174x; 1.0758x over previous
//
#include <hip/hip_runtime.h>

// out[b,h] = (X X^T) X == X (X^T X) per head; X = x[b,h] : [2048 x 64] fp32.
// MFMA bf16 (fp32 accumulate), 3 dispatches, occupancy-tuned:
//  K1 (512 blocks, 128-row chunks): global->reg (8 rows x 4 cols / thread),
//     f2bf, transpose via 4x ds_write_b128 into swizzled XT; 16 MFMA/wave;
//     partial G stored PACKED bf16 lane-major (512 B/instr coalesced).
//  K2a (128 blocks): fixed-order fp32 reduce of 16 bf16 partials -> G;
//     emits PRE-SWIZZLED bf16 G image (m173) for K2b's linear DMA.
//  K2b (1024 blocks, 64-row tiles): reg-stage f32 X (no LDS round-trip) +
//     DMA G concurrently; one barrier; 8 MFMA/wave; out.
// C/D layout per m89: col = lane&15, row = (lane>>4)*4 + reg.

#define TDIM 2048
#define DDIM 64
#define NHEADS 32
#define NCH 16                                    // 128-row chunks per head

typedef float f4 __attribute__((ext_vector_type(4)));
typedef float f32x4 __attribute__((ext_vector_type(4)));
typedef short bf16x8 __attribute__((ext_vector_type(8)));
typedef short s4 __attribute__((ext_vector_type(4)));

// Async global->LDS DMA, 16 B/lane. LDS dest wave-uniform; lane l -> dest+l*16.
__device__ __forceinline__ void async_copy16(const void* g, void* l) {
    __builtin_amdgcn_global_load_lds(
        (const __attribute__((address_space(1))) void*)g,
        (__attribute__((address_space(3))) void*)l, 16, 0, 0);
}

// f32 -> bf16 bits (RNE) and back.
__device__ __forceinline__ short f2bf(float f) {
    unsigned u = __builtin_bit_cast(unsigned, f);
    unsigned r = (u + 0x7fffu + ((u >> 16) & 1u)) >> 16;
    return (short)r;
}
__device__ __forceinline__ float bf2f(short s) {
    return __builtin_bit_cast(float, ((unsigned)(unsigned short)s) << 16);
}

// Swizzled fragment pointer: row-major bf16 tile (rowlen shorts/row); byte
// offset within row = (kelem*2) ^ ((row&7)<<4). 16 B alignment preserved.
__device__ __forceinline__ const bf16x8* fragp(const short* base, int row,
                                               int rowlen, int kelem) {
    const char* p = (const char*)(base + row * rowlen);
    return (const bf16x8*)(p + ((kelem * 2) ^ ((row & 7) << 4)));
}

// ---------------- K1: partial Gram ----------------
__global__ __launch_bounds__(256) void k1_gram(const float* __restrict__ x,
                                               short* __restrict__ part) {
    __shared__ __align__(16) short XT[64 * 128];  // 16 KB transposed swz bf16

    const int b    = blockIdx.x;        // 0..511
    const int tid  = threadIdx.x;
    const int lane = tid & 63;
    const int w    = tid >> 6;
    const int head = b >> 4, ch = b & 15;

    const float* xh = x + ((size_t)head * TDIM + ch * 128) * DDIM;

    // Thread owns rows r0..r0+7 x cols c4..c4+3.
    const int rg = tid >> 4, cg = tid & 15;
    const int r0 = rg * 8, c4 = cg * 4;

    f4 v[8];
#pragma unroll
    for (int k = 0; k < 8; ++k)
        v[k] = *reinterpret_cast<const f4*>(xh + (size_t)(r0 + k) * DDIM + c4);

    // Transpose: one b128 (8 t-contiguous bf16) per column.
#pragma unroll
    for (int j = 0; j < 4; ++j) {
        bf16x8 pk;
#pragma unroll
        for (int k = 0; k < 8; ++k) pk[k] = f2bf(v[k][j]);
        const int c = c4 + j;
        *(bf16x8*)((char*)XT + c * 256 + ((2 * r0) ^ ((c & 7) << 4))) = pk;
    }
    __syncthreads();

    // Gram MFMA over K=128: wave w owns 2x2 quad of 16x16 G tiles.
    const int li = lane & 15, g = lane >> 4;
    const int iq0 = (w >> 1) * 2, jq0 = (w & 1) * 2;

    f32x4 acc[2][2];
#pragma unroll
    for (int a = 0; a < 2; ++a)
#pragma unroll
        for (int q = 0; q < 2; ++q) acc[a][q] = (f32x4){0.f, 0.f, 0.f, 0.f};

#pragma unroll
    for (int k0 = 0; k0 < 128; k0 += 32) {
        bf16x8 af[2], bv[2];
        af[0] = *fragp(XT, (iq0 + 0) * 16 + li, 128, k0 + 8 * g);
        af[1] = *fragp(XT, (iq0 + 1) * 16 + li, 128, k0 + 8 * g);
        bv[0] = *fragp(XT, (jq0 + 0) * 16 + li, 128, k0 + 8 * g);
        bv[1] = *fragp(XT, (jq0 + 1) * 16 + li, 128, k0 + 8 * g);
#pragma unroll
        for (int a = 0; a < 2; ++a)
#pragma unroll
            for (int q = 0; q < 2; ++q)
                acc[a][q] = __builtin_amdgcn_mfma_f32_16x16x32_bf16(
                    af[a], bv[q], acc[a][q], 0, 0, 0);
    }

    // Packed bf16 partial store: s4 index f = ((w*2+a)*2+d)*64 + lane.
    short* pp = part + (size_t)b * 4096;
#pragma unroll
    for (int a = 0; a < 2; ++a)
#pragma unroll
        for (int d = 0; d < 2; ++d) {
            s4 pk;
#pragma unroll
            for (int q = 0; q < 4; ++q) pk[q] = f2bf(acc[a][d][q]);
            *(s4*)(pp + ((((w * 2 + a) * 2 + d) * 64 + lane) << 2)) = pk;
        }
}

// ---------------- K2a: reduce packed partials -> pre-swizzled bf16 G --------
__global__ __launch_bounds__(256) void k2a_reduce(const short* __restrict__ part,
                                                  short* __restrict__ gbf) {
    const int b    = blockIdx.x;        // 0..127
    const int tid  = threadIdx.x;
    const int head = b >> 2, quarter = b & 3;

    const int f = quarter * 256 + tid;  // s4 index within chunk, 0..1023
    const short* ph = part + (size_t)head * NCH * 4096 + (f << 2);

    float s[4] = {0.f, 0.f, 0.f, 0.f};
#pragma unroll
    for (int c = 0; c < NCH; ++c) {
        const s4 v = *reinterpret_cast<const s4*>(ph + (size_t)c * 4096);
#pragma unroll
        for (int q = 0; q < 4; ++q) s[q] += bf2f(v[q]);
    }

    // decode f -> (w,a,d,lane) -> (i,j) and store swizzled G image.
    const int lane = f & 63, wad = f >> 6;
    const int w = wad >> 2, a = (wad >> 1) & 1, d = wad & 1;
    const int g = lane >> 4, li = lane & 15;
    const int iq0 = (w >> 1) * 2, jq0 = (w & 1) * 2;
    const int j = (jq0 + d) * 16 + li;
    char* gb = (char*)gbf + (size_t)head * 8192;
#pragma unroll
    for (int q = 0; q < 4; ++q) {
        const int i = (iq0 + a) * 16 + g * 4 + q;
        *(short*)(gb + i * 128 + ((2 * j) ^ ((i & 7) << 4))) = f2bf(s[q]);
    }
}

// ---------------- K2b: out = X*G via MFMA (reg-staged X, 1 barrier) ---------
__global__ __launch_bounds__(256) void k2b_xg(const float* __restrict__ x,
                                              float* __restrict__ out,
                                              const short* __restrict__ gbf) {
    __shared__ __align__(16) short Xb[4096];      // 8 KB bf16 swz
    __shared__ __align__(16) short Gb[4096];      // 8 KB bf16 G swz

    const int b    = blockIdx.x;        // 0..1023
    const int tid  = threadIdx.x;
    const int lane = tid & 63;
    const int w    = tid >> 6;
    const int head = b >> 5, ch = b & 31;

    {   // DMA bf16 G image (8 KB, linear; pre-swizzled at write time)
        const short* gg = gbf + (size_t)head * 4096 + w * 1024 + lane * 8;
        short* lg = Gb + w * 1024;
#pragma unroll
        for (int it = 0; it < 2; ++it)
            async_copy16(gg + it * 512, lg + it * 512);
    }

    // Reg-stage X tile (64x64 f32), convert, swizzled LDS writes.
    const float* xh = x + ((size_t)head * TDIM + ch * 64) * DDIM;
#pragma unroll
    for (int e = 0; e < 4; ++e) {
        const int i4 = e * 256 + tid;            // f4 index in 64x64 tile
        const int r  = i4 >> 4;
        const int c4 = (i4 & 15) << 2;
        const f4 v = *reinterpret_cast<const f4*>(xh + (size_t)i4 * 4);
        s4 pk;
        pk[0] = f2bf(v[0]); pk[1] = f2bf(v[1]);
        pk[2] = f2bf(v[2]); pk[3] = f2bf(v[3]);
        *(s4*)((char*)Xb + r * 128 + ((2 * c4) ^ ((r & 7) << 4))) = pk;
    }
    __syncthreads();   // drains G DMA (vmcnt) + Xb writes (lgkmcnt)

    // MFMA: wave w owns row-tile w (16 rows) x 4 col-tiles, K=64.
    const int li = lane & 15, g = lane >> 4;

    f32x4 acc[4];
#pragma unroll
    for (int d = 0; d < 4; ++d) acc[d] = (f32x4){0.f, 0.f, 0.f, 0.f};

#pragma unroll
    for (int k0 = 0; k0 < 64; k0 += 32) {
        bf16x8 af, bv[4];
        af = *fragp(Xb, w * 16 + li, 64, k0 + 8 * g);
#pragma unroll
        for (int d = 0; d < 4; ++d)
            bv[d] = *fragp(Gb, d * 16 + li, 64, k0 + 8 * g);
#pragma unroll
        for (int d = 0; d < 4; ++d)
            acc[d] = __builtin_amdgcn_mfma_f32_16x16x32_bf16(
                af, bv[d], acc[d], 0, 0, 0);
    }

    float* oh = out + ((size_t)head * TDIM + ch * 64) * DDIM;
#pragma unroll
    for (int d = 0; d < 4; ++d)
#pragma unroll
        for (int q = 0; q < 4; ++q)
            oh[(w * 16 + g * 4 + q) * 64 + d * 16 + li] = acc[d][q];
}

extern "C" void kernel_launch(void* const* d_in, const int* in_sizes, int n_in,
                              void* d_out, int out_size, void* d_ws, size_t ws_size,
                              hipStream_t stream) {
    const float* x = (const float*)d_in[0];
    float* out  = (float*)d_out;
    short* part = (short*)d_ws;                          // 512*8KB = 4.2 MB
    short* gbf  = part + (size_t)512 * 4096;             // 256 KB

    k1_gram<<<NHEADS * NCH, 256, 0, stream>>>(x, part);
    k2a_reduce<<<128, 256, 0, stream>>>(part, gbf);
    k2b_xg<<<NHEADS * 32, 256, 0, stream>>>(x, out, gbf);
}